// Round 6
// baseline (54243.298 us; speedup 1.0000x reference)
//
#include <hip/hip_runtime.h>
#include <math.h>

// NDDE forward-Euler DDE solve, D=768, N=8192 steps.
// x_{j+1} = x_j + dt * tanh(Wx x_j + Wy x_{j-10} + b),  dt = tau/10.
// Output: trajectory [D][N+1] fp32, out[i*(N+1)+k] = x_k[i].
//
// NUMERICS ARE FROZEN (passes at absmax 16.0 / thr 16.4): fp64-exact dots
// rounded per-dot to fp32; fp32 adds for z; correctly-rounded fp32 tanh via
// fp64; fp32 state update mul-then-add; identical per-lane column ownership,
// FMA order, and shuffle reduction tree. Round 6 changes ONLY scheduling and
// where the (exact) f32->f64 conversions happen — every double value entering
// every FMA is bit-identical to rounds 3-5.
//
// Structure: 96 WGs x 320 thr. Wave 0 = dedicated poller/broadcaster;
// waves 1-4 = compute, rows [8g, 8g+8), 32 lanes/row, 24 cols/lane.
// Producers publish (value|tag) 8B packs to a global ring with relaxed
// agent-scope atomic stores (no fences). Wave 0 dual-stream polls the 768
// tags (12/lane, two batches in flight => detection granularity ~RT/2),
// converts once to f64, broadcasts into a 16-slot f64 LDS history in a
// transposed bank-friendly layout. Compute waves: y-dot (overlaps the poll)
// -> barrier -> x-dot -> reduce -> tanh -> publish. Weights live as f64 in
// 96 pinned VGPRs (pinned in-loop so they cannot spill).

#define DD 768
#define NSTEPS 8192
#define NWG 96
#define NT 320
#define ROWS_PER_WG 8
#define COLS_PER_LANE 24
#define RING 16

#define RING_OFF 0   // RING * DD * 8B in d_ws

__device__ __forceinline__ unsigned long long ld_tag(const unsigned long long* p) {
    return __hip_atomic_load(p, __ATOMIC_RELAXED, __HIP_MEMORY_SCOPE_AGENT);
}

__global__ __launch_bounds__(NT, 1)
void ndde_kernel(const float* __restrict__ x0,
                 const float* __restrict__ tau,
                 const float* __restrict__ Wx,
                 const float* __restrict__ Wy,
                 const float* __restrict__ b,
                 float* __restrict__ out,
                 unsigned long long* __restrict__ ring)
{
    // Transposed f64 LDS history: column i lives at hist[slot][(i%24)*32+i/24].
    // Read by lane c at [k*32+c] (banks 2c,2c+1: 2-way on b64 = free, m136);
    // written by wave-0 (once/step, ~4-way, negligible).
    __shared__ double hist[RING][DD];    // 96 KB

    const int tid    = threadIdx.x;
    const int g      = blockIdx.x;
    const bool pollw = (tid < 64);       // wave 0 = poller (wave-uniform)
    const int r      = (tid >> 5) - 2;   // compute: local row 0..7
    const int c      = tid & 31;         // lane-within-row 0..31
    const int row    = g * ROWS_PER_WG + r;
    const int cb     = c * COLS_PER_LANE;

    const float dtf = tau[0] / 10.0f;

    // ---- compute waves: stage weights, cvt f32->f64 ONCE (exact) ----
    double wx[COLS_PER_LANE], wy[COLS_PER_LANE];
    float brow = 0.0f, xrow = 0.0f;
    if (!pollw) {
        const float* px = Wx + row * DD + cb;
        const float* py = Wy + row * DD + cb;
        #pragma unroll
        for (int i = 0; i < COLS_PER_LANE / 4; ++i) {
            float4 a = *(const float4*)(px + 4 * i);
            wx[4*i+0] = (double)a.x; wx[4*i+1] = (double)a.y;
            wx[4*i+2] = (double)a.z; wx[4*i+3] = (double)a.w;
            float4 d2 = *(const float4*)(py + 4 * i);
            wy[4*i+0] = (double)d2.x; wy[4*i+1] = (double)d2.y;
            wy[4*i+2] = (double)d2.z; wy[4*i+3] = (double)d2.w;
        }
        brow = b[row];
        xrow = x0[row];                  // lane c==0 carries x_j[row]
        if (c == 0) out[row * (NSTEPS + 1) + 0] = xrow;
    } else {
        __builtin_amdgcn_s_setprio(1);   // poller wave is latency-critical
    }

    for (int j = 0; j < NSTEPS; ++j) {
        if (pollw) {
            // ---- dual-stream poll of all 768 tags (12/lane), then f64
            // broadcast into LDS slot j. Starts immediately after the
            // previous barrier — no dot work delays it. ----
            if (j >= 1) {
                const unsigned tgt = (unsigned)j;
                const unsigned long long* xs =
                    ring + (j & (RING - 1)) * DD + tid * 12;
                unsigned long long xa[12], xb[12], xv[12];
                #pragma unroll
                for (int m = 0; m < 12; ++m) xa[m] = ld_tag(xs + m);
                for (;;) {
                    #pragma unroll
                    for (int m = 0; m < 12; ++m) xb[m] = ld_tag(xs + m);
                    bool ok = true;
                    #pragma unroll
                    for (int m = 0; m < 12; ++m)
                        ok &= ((unsigned)(xa[m] >> 32) == tgt);
                    if (__all(ok)) {
                        #pragma unroll
                        for (int m = 0; m < 12; ++m) xv[m] = xa[m];
                        break;
                    }
                    #pragma unroll
                    for (int m = 0; m < 12; ++m) xa[m] = ld_tag(xs + m);
                    ok = true;
                    #pragma unroll
                    for (int m = 0; m < 12; ++m)
                        ok &= ((unsigned)(xb[m] >> 32) == tgt);
                    if (__all(ok)) {
                        #pragma unroll
                        for (int m = 0; m < 12; ++m) xv[m] = xb[m];
                        break;
                    }
                }
                double* hs = hist[j & (RING - 1)];
                #pragma unroll
                for (int m = 0; m < 12; ++m) {
                    int i = tid * 12 + m;
                    hs[(i % 24) * 32 + (i / 24)] =
                        (double)__uint_as_float((unsigned)xv[m]);  // exact cvt
                }
            }
            __syncthreads();
            // poller has no post-barrier work; loops straight to j+1
        } else {
            // re-pin weights every iteration: spilling them is impossible
            #pragma unroll
            for (int i = 0; i < COLS_PER_LANE; ++i) {
                asm volatile("" : "+v"(wx[i]));
                asm volatile("" : "+v"(wy[i]));
            }

            // ---- delayed half: y = x_{j-10}; overlaps wave-0's polling ----
            double dy0 = 0.0, dy1 = 0.0;
            if (j <= 10) {
                const float* ys = x0 + cb;
                #pragma unroll
                for (int i = 0; i < COLS_PER_LANE / 4; ++i) {
                    float4 v = *(const float4*)(ys + 4 * i);
                    dy0 = fma(wy[4*i+0], (double)v.x, dy0);
                    dy1 = fma(wy[4*i+1], (double)v.y, dy1);
                    dy0 = fma(wy[4*i+2], (double)v.z, dy0);
                    dy1 = fma(wy[4*i+3], (double)v.w, dy1);
                }
            } else {
                const double* hs = hist[(j - 10) & (RING - 1)];
                #pragma unroll
                for (int k = 0; k < COLS_PER_LANE; k += 4) {
                    double v0 = hs[(k+0)*32 + c];
                    double v1 = hs[(k+1)*32 + c];
                    double v2 = hs[(k+2)*32 + c];
                    double v3 = hs[(k+3)*32 + c];
                    dy0 = fma(wy[k+0], v0, dy0);
                    dy1 = fma(wy[k+1], v1, dy1);
                    dy0 = fma(wy[k+2], v2, dy0);
                    dy1 = fma(wy[k+3], v3, dy1);
                }
            }
            double doty = dy0 + dy1;
            #pragma unroll
            for (int off = 1; off < 32; off <<= 1)
                doty += __shfl_xor(doty, off);

            __syncthreads();             // wait for wave 0's broadcast

            // ---- live half: Wx · x_j from f64 LDS (x0 global at j==0) ----
            double dx0 = 0.0, dx1 = 0.0;
            if (j == 0) {
                const float* xs = x0 + cb;
                #pragma unroll
                for (int i = 0; i < COLS_PER_LANE / 4; ++i) {
                    float4 v = *(const float4*)(xs + 4 * i);
                    dx0 = fma(wx[4*i+0], (double)v.x, dx0);
                    dx1 = fma(wx[4*i+1], (double)v.y, dx1);
                    dx0 = fma(wx[4*i+2], (double)v.z, dx0);
                    dx1 = fma(wx[4*i+3], (double)v.w, dx1);
                }
            } else {
                const double* hs = hist[j & (RING - 1)];
                #pragma unroll
                for (int k = 0; k < COLS_PER_LANE; k += 4) {
                    double v0 = hs[(k+0)*32 + c];
                    double v1 = hs[(k+1)*32 + c];
                    double v2 = hs[(k+2)*32 + c];
                    double v3 = hs[(k+3)*32 + c];
                    dx0 = fma(wx[k+0], v0, dx0);
                    dx1 = fma(wx[k+1], v1, dx1);
                    dx0 = fma(wx[k+2], v2, dx0);
                    dx1 = fma(wx[k+3], v3, dx1);
                }
            }
            double dotx = dx0 + dx1;
            #pragma unroll
            for (int off = 1; off < 32; off <<= 1)
                dotx += __shfl_xor(dotx, off);

            if (c == 0) {
                // z = (dot1_f32 + dot2_f32) + b, all fp32 adds
                float z = __fadd_rn(__fadd_rn((float)dotx, (float)doty), brow);
                float th;
                float az = fabsf(z);
                if (az < 9.3f) th = (float)tanh((double)z);  // correctly-rounded
                else           th = (z > 0.0f) ? 1.0f : -1.0f;
                // x_next = x + dt*F, fp32 mul then fp32 add (no contraction)
                xrow = __fadd_rn(xrow, __fmul_rn(dtf, th));

                // publish: value and tag in one relaxed agent-scope 8B store
                unsigned long long pack =
                    ((unsigned long long)(unsigned)(j + 1) << 32) |
                    (unsigned long long)__float_as_uint(xrow);
                __hip_atomic_store(&ring[((j + 1) & (RING - 1)) * DD + row],
                                   pack, __ATOMIC_RELAXED,
                                   __HIP_MEMORY_SCOPE_AGENT);

                // trajectory write — off the critical path
                out[row * (NSTEPS + 1) + (j + 1)] = xrow;
            }
        }
    }
}

extern "C" void kernel_launch(void* const* d_in, const int* in_sizes, int n_in,
                              void* d_out, int out_size, void* d_ws, size_t ws_size,
                              hipStream_t stream) {
    (void)in_sizes; (void)n_in; (void)out_size; (void)ws_size;

    const float* x0  = (const float*)d_in[0];
    const float* tau = (const float*)d_in[1];
    const float* Wx  = (const float*)d_in[2];
    const float* Wy  = (const float*)d_in[3];
    const float* b   = (const float*)d_in[4];
    float* out = (float*)d_out;

    unsigned long long* ring = (unsigned long long*)((char*)d_ws + RING_OFF);

    // No memset needed: strict tag==j matching rejects 0xAA poison and stale
    // tags from a previous replay (slot j%16 is freshly rewritten every 16
    // steps, and leftover end-of-run tags (~8180+) never equal an early j).
    ndde_kernel<<<NWG, NT, 0, stream>>>(x0, tau, Wx, Wy, b, out, ring);
}